// Round 9
// baseline (1195.010 us; speedup 1.0000x reference)
//
#include <hip/hip_runtime.h>

// Round 9: r8 + producer-flag sync (no per-step barrier) + ring-prefetched
// global B-frags. XCD-local persistent GRU, 8 groups x 32 blocks x 512 thr.

typedef unsigned short ushort_t;
typedef __bf16 bf16x8 __attribute__((ext_vector_type(8)));
typedef float f32x4 __attribute__((ext_vector_type(4)));
typedef unsigned int u32x4 __attribute__((ext_vector_type(4)));

#define MFMA(a, b, c) __builtin_amdgcn_mfma_f32_16x16x32_bf16(a, b, c, 0, 0, 0)
#define AL(p) __hip_atomic_load(p, __ATOMIC_RELAXED, __HIP_MEMORY_SCOPE_AGENT)
#define AS(p, v) __hip_atomic_store(p, v, __ATOMIC_RELAXED, __HIP_MEMORY_SCOPE_AGENT)

static __device__ __forceinline__ ushort_t f2bf(float f) {
  union { float f; unsigned u; } x; x.f = f;
  unsigned r = x.u + 0x7fffu + ((x.u >> 16) & 1u);
  return (ushort_t)(r >> 16);
}
static __device__ __forceinline__ float sigmf(float x) { return 1.f / (1.f + __expf(-x)); }
static __device__ __forceinline__ float tanhf_(float x) { return 1.f - 2.f / (__expf(2.f * x) + 1.f); }

static __device__ __forceinline__ __amdgpu_buffer_rsrc_t mkrsrc(const void* p) {
  return __builtin_amdgcn_make_buffer_rsrc(const_cast<void*>(p), (short)0, -1, 0x00020000);
}
#if __has_builtin(__builtin_amdgcn_raw_buffer_load_b128)
static __device__ __forceinline__ bf16x8 ldb(__amdgpu_buffer_rsrc_t r, int voff) {
  u32x4 v = __builtin_amdgcn_raw_buffer_load_b128(r, voff, 0, 1);
  union { u32x4 u; bf16x8 b; } x; x.u = v; return x.b;
}
#else
static __device__ __forceinline__ bf16x8 ldb(__amdgpu_buffer_rsrc_t r, int voff) {
  union { unsigned u[4]; bf16x8 b; } x;
  x.u[0] = __builtin_amdgcn_raw_buffer_load_b32(r, voff, 0, 1);
  x.u[1] = __builtin_amdgcn_raw_buffer_load_b32(r, voff + 4, 0, 1);
  x.u[2] = __builtin_amdgcn_raw_buffer_load_b32(r, voff + 8, 0, 1);
  x.u[3] = __builtin_amdgcn_raw_buffer_load_b32(r, voff + 12, 0, 1);
  return x.b;
}
#endif

__global__ __launch_bounds__(512, 2)
void seq2seq_xcd(const float* __restrict__ enc, const float* __restrict__ dec,
                 const float* __restrict__ Wih, const float* __restrict__ Whh,
                 const float* __restrict__ b_ih, const float* __restrict__ b_hh,
                 const float* __restrict__ fcw, const float* __restrict__ fcb,
                 float* __restrict__ outp,
                 ushort_t* __restrict__ xg, ushort_t* __restrict__ hA,
                 ushort_t* __restrict__ innA, ushort_t* __restrict__ nG,
                 ushort_t* __restrict__ wiG, ushort_t* __restrict__ fcG,
                 unsigned* cnt) {
  __shared__ ushort_t WrzL[65536];  // [kt32][gate2(r,z)][jf2][ln64][8]  128 KB
  __shared__ float scr[6144];       // kreduce scratch                    24 KB
  __shared__ unsigned sgs;

  const int tid = threadIdx.x;
  const int w = tid >> 6, l = tid & 63;
  const int fr = l & 15, fq4 = l >> 4;

  // ---- claim XCD-local slot ----
  if (tid == 0) {
    unsigned x;
    asm volatile("s_getreg_b32 %0, hwreg(HW_REG_XCC_ID, 0, 8)" : "=s"(x));
    x &= 7u;
    unsigned s = atomicAdd(&cnt[x * 64], 1u);
    sgs = (x << 8) | s;
  }
  __syncthreads();
  const int g = sgs >> 8, slot = sgs & 255;

  unsigned* arrp = cnt + (8 + g) * 64;
  unsigned* relp = cnt + (16 + g * 4 + (slot & 3)) * 64;
  unsigned* relw = cnt + (16 + g * 4) * 64;
  auto fcpp = [&](int td) { return cnt + (48 + g * 25 + td) * 64; };
  unsigned* flagg = cnt + 16384 + g * 512;  // 32 flags x 16 dwords (64B lines)

  ushort_t* hbase = hA + (size_t)g * 262144;
  auto hb = [&](int i) { return hbase + (size_t)i * 131072; };
  ushort_t* xgg = xg + (size_t)g * 49 * 8192;
  auto inng = [&](int i) { return innA + (size_t)(g * 2 + i) * 8192; };
  ushort_t* nGp = nG + (size_t)(g * 32 + slot) * 32768;
  ushort_t* wiGp = wiG + (size_t)(g * 32 + slot) * 8192;
  ushort_t* fcGg = fcG + (size_t)g * 65536;

  // ---- init (same as r8) ----
  {
    const int q = tid & 127, cc = tid >> 7;
    const int kt = q >> 2, lnp = (q & 3) * 16;
#pragma unroll
    for (int p = cc; p < 64; p += 4) {
      int gt = p >> 5, c = p & 31;
      const float* src = Whh + (size_t)(gt * 1024 + slot * 32 + c) * 1024 + q * 8;
      ushort_t* dst = WrzL + kt * 2048 + gt * 1024 + (c >> 4) * 512 + ((c & 15) + lnp) * 8;
#pragma unroll
      for (int j = 0; j < 8; ++j) dst[j] = f2bf(src[j]);
    }
#pragma unroll
    for (int p = cc; p < 32; p += 4) {
      const float* src = Whh + (size_t)(2048 + slot * 32 + p) * 1024 + q * 8;
      ushort_t* dst = nGp + kt * 1024 + (p >> 4) * 512 + ((p & 15) + lnp) * 8;
#pragma unroll
      for (int j = 0; j < 8; ++j) dst[j] = f2bf(src[j]);
    }
  }
  for (int i = tid; i < 6144; i += 512) {
    int j = i & 7, ln = (i >> 3) & 63, jf = (i >> 9) & 1, rem = i >> 10;
    int gt = rem % 3, kt = rem / 3;
    int col = gt * 1024 + slot * 32 + jf * 16 + (ln & 15);
    int k = kt * 32 + (ln >> 4) * 8 + j;
    wiGp[i] = (k < 55) ? f2bf(Wih[(size_t)col * 55 + k]) : (ushort_t)0;
  }
#pragma unroll
  for (int rep = 0; rep < 2; ++rep) {
    int t = slot + rep * 32;
    if (t < 49) {
      ushort_t* xp = xgg + (size_t)t * 8192;
      for (int i = tid; i < 8192; i += 512) {
        int sub = i & 7, row = (i >> 3) & 127, kc = i >> 10;
        int c = kc * 8 + sub;
        xp[i] = (c < 55) ? f2bf(enc[((size_t)(g * 128 + row) * 50 + t) * 55 + c]) : (ushort_t)0;
      }
    }
  }
  if (slot < 4) {
    ushort_t* ip = inng(0);
    for (int i = slot * 2048 + tid; i < (slot + 1) * 2048; i += 512) {
      int sub = i & 7, row = (i >> 3) & 127, kc = i >> 10;
      int c = kc * 8 + sub;
      ip[i] = (c < 55) ? f2bf(dec[(size_t)(g * 128 + row) * 1375 + c]) : (ushort_t)0;
    }
  }
  if (slot >= 24) {
    for (int i = (slot - 24) * 8192 + tid; i < (slot - 23) * 8192; i += 512) {
      int j = i & 7, ln = (i >> 3) & 63, jf = (i >> 9) & 3, kt = i >> 11;
      int c = jf * 16 + (ln & 15);
      int k = kt * 32 + (ln >> 4) * 8 + j;
      fcGg[i] = (c < 55) ? f2bf(fcw[(size_t)c * 1024 + k]) : (ushort_t)0;
    }
  }

  // ---- per-thread constants ----
  float brz[2], bzz[2], bin[2], bhn[2];
#pragma unroll
  for (int jf = 0; jf < 2; ++jf) {
    int col = slot * 32 + jf * 16 + fr;
    brz[jf] = b_ih[col] + b_hh[col];
    bzz[jf] = b_ih[1024 + col] + b_hh[1024 + col];
    bin[jf] = b_ih[2048 + col];
    bhn[jf] = b_hh[2048 + col];
  }
  const int rT = slot & 7, cT = slot >> 3;
  const int colF = cT * 16 + fr;
  float fcbF = 0.f, inp[4] = {0.f, 0.f, 0.f, 0.f};
  if (w == 4) {
    fcbF = (colF < 55) ? fcb[colF] : 0.f;
#pragma unroll
    for (int v = 0; v < 4; ++v)
      inp[v] = (colF < 55) ? dec[(size_t)(g * 128 + rT * 16 + fq4 * 4 + v) * 1375 + colF] : 0.f;
  }
  f32x4 hreg[4];
#pragma unroll
  for (int i = 0; i < 4; ++i) hreg[i] = (f32x4){0.f, 0.f, 0.f, 0.f};

  // ---- init-only barrier (master/slave, once) ----
  auto arrive = [&](unsigned k) {
    __syncthreads();
    if (tid == 0) {
      if (slot == 0) {
        while (AL(arrp) < 31u * k) __builtin_amdgcn_s_sleep(1);
#pragma unroll
        for (int s = 0; s < 4; ++s) AS(relw + s * 64, k);
      } else {
        atomicAdd(arrp, 1u);
      }
    }
  };
  auto wait_rel = [&](unsigned k) {
    __syncthreads();
    if (tid == 0) {
      while (AL(relp) < k) __builtin_amdgcn_s_sleep(1);
    }
    __syncthreads();
  };
  auto fc_wait = [&](int td) {
    __syncthreads();
    if (tid == 0) {
      while (AL(fcpp(td)) < 32u) __builtin_amdgcn_s_sleep(1);
    }
    __syncthreads();
  };

  f32x4 av[12], nx[4];

  auto xpart = [&](const ushort_t* xp) {  // waves 0-3, full K=64
    __amdgpu_buffer_rsrc_t rx = mkrsrc(xp);
    const int R = w * 32;
#pragma unroll
    for (int kt = 0; kt < 2; ++kt) {
      bf16x8 a0 = ldb(rx, ((kt * 4 + fq4) * 128 + R + fr) * 16);
      bf16x8 a1 = ldb(rx, ((kt * 4 + fq4) * 128 + R + 16 + fr) * 16);
      const ushort_t* bl = wiGp + kt * 3072 + l * 8;
#pragma unroll
      for (int jf = 0; jf < 2; ++jf) {
        bf16x8 br = *(const bf16x8*)(bl + jf * 512);
        bf16x8 bz = *(const bf16x8*)(bl + 1024 + jf * 512);
        bf16x8 bn = *(const bf16x8*)(bl + 2048 + jf * 512);
        av[jf] = MFMA(a0, br, av[jf]);
        av[2 + jf] = MFMA(a1, br, av[2 + jf]);
        av[4 + jf] = MFMA(a0, bz, av[4 + jf]);
        av[6 + jf] = MFMA(a1, bz, av[6 + jf]);
        nx[jf] = MFMA(a0, bn, nx[jf]);
        nx[2 + jf] = MFMA(a1, bn, nx[2 + jf]);
      }
    }
  };

  // Distributed sense-wait: lanes check the 16 producers of this K-half.
  auto waitHalf = [&](int kh, unsigned need) {
    const unsigned* fp = flagg + (kh * 16 + (l & 15)) * 16;
    for (;;) {
      unsigned v = AL(fp);
      if (__ballot(v >= need) == ~0ull) break;
      __builtin_amdgcn_s_sleep(1);
    }
  };
  auto waitAll = [&](unsigned need) {  // all 32 producers (wave-4 FC)
    const unsigned* fp = flagg + (l & 31) * 16;
    for (;;) {
      unsigned v = AL(fp);
      if (__ballot(v >= need) == ~0ull) break;
      __builtin_amdgcn_s_sleep(1);
    }
  };

  auto hpart = [&](const ushort_t* hbp, unsigned need) {
    __amdgpu_buffer_rsrc_t rb = mkrsrc(hbp);
    const int kh = w >> 2, R = (w & 3) * 32;
    waitHalf(kh, need);
    int kts[16];
#pragma unroll
    for (int i = 0; i < 16; ++i) kts[i] = kh * 16 + ((slot + 1 + i) & 15);
    bf16x8 A0[8], A1[8];
#pragma unroll
    for (int i = 0; i < 8; ++i) {
      int kt = kts[i];
      A0[i] = ldb(rb, ((kt * 4 + fq4) * 128 + R + fr) * 16);
      A1[i] = ldb(rb, ((kt * 4 + fq4) * 128 + R + 16 + fr) * 16);
    }
    bf16x8 BN[2][2];
#pragma unroll
    for (int i = 0; i < 2; ++i) {
      const ushort_t* np = nGp + kts[i] * 1024 + l * 8;
      BN[i][0] = *(const bf16x8*)(np);
      BN[i][1] = *(const bf16x8*)(np + 512);
    }
#pragma unroll
    for (int i = 0; i < 16; ++i) {
      int kt = kts[i];
      bf16x8 a0 = A0[i & 7], a1 = A1[i & 7];
      bf16x8 bn0 = BN[i & 1][0], bn1 = BN[i & 1][1];
      if (i < 8) {
        int kp = kts[i + 8];
        A0[i & 7] = ldb(rb, ((kp * 4 + fq4) * 128 + R + fr) * 16);
        A1[i & 7] = ldb(rb, ((kp * 4 + fq4) * 128 + R + 16 + fr) * 16);
      }
      if (i < 14) {
        const ushort_t* np = nGp + kts[i + 2] * 1024 + l * 8;
        BN[i & 1][0] = *(const bf16x8*)(np);
        BN[i & 1][1] = *(const bf16x8*)(np + 512);
      }
      const ushort_t* bl = WrzL + kt * 2048 + l * 8;
#pragma unroll
      for (int jf = 0; jf < 2; ++jf) {
        bf16x8 br = *(const bf16x8*)(bl + jf * 512);
        bf16x8 bz = *(const bf16x8*)(bl + 1024 + jf * 512);
        bf16x8 bn = jf ? bn1 : bn0;
        av[jf] = MFMA(a0, br, av[jf]);
        av[2 + jf] = MFMA(a1, br, av[2 + jf]);
        av[4 + jf] = MFMA(a0, bz, av[4 + jf]);
        av[6 + jf] = MFMA(a1, bz, av[6 + jf]);
        av[8 + jf] = MFMA(a0, bn, av[8 + jf]);
        av[10 + jf] = MFMA(a1, bn, av[10 + jf]);
      }
    }
  };

  auto kreduce = [&]() {
#pragma unroll
    for (int rd = 0; rd < 2; ++rd) {
      if (w >= 4) {
#pragma unroll
        for (int j = 0; j < 6; ++j)
          *(f32x4*)(scr + ((j * 4 + (w - 4)) * 64 + l) * 4) = av[rd * 6 + j];
      }
      __syncthreads();
      if (w < 4) {
#pragma unroll
        for (int j = 0; j < 6; ++j)
          av[rd * 6 + j] += *(const f32x4*)(scr + ((j * 4 + w) * 64 + l) * 4);
      }
      __syncthreads();
    }
  };

  // Decoder FC tile (wave 4 only), flag-gated, ring-prefetched.
  auto fcdo = [&](const ushort_t* hbp, int td, bool wr, unsigned need) {
    __amdgpu_buffer_rsrc_t rb = mkrsrc(hbp);
    const int rowb = (rT * 16 + fr) * 16;
    waitAll(need);
    int ko[32];
#pragma unroll
    for (int i = 0; i < 32; ++i) ko[i] = (slot + 1 + i) & 31;
    f32x4 fa = (f32x4){0.f, 0.f, 0.f, 0.f};
    bf16x8 Af[4];
#pragma unroll
    for (int i = 0; i < 4; ++i) Af[i] = ldb(rb, (ko[i] * 4 + fq4) * 2048 + rowb);
    bf16x8 BF[2];
#pragma unroll
    for (int i = 0; i < 2; ++i)
      BF[i] = *(const bf16x8*)(fcGg + ko[i] * 2048 + cT * 512 + l * 8);
#pragma unroll
    for (int i = 0; i < 32; ++i) {
      bf16x8 a = Af[i & 3], bf = BF[i & 1];
      if (i < 28) Af[i & 3] = ldb(rb, (ko[i + 4] * 4 + fq4) * 2048 + rowb);
      if (i < 30) BF[i & 1] = *(const bf16x8*)(fcGg + ko[i + 2] * 2048 + cT * 512 + l * 8);
      fa = MFMA(a, bf, fa);
    }
    const int kq = colF >> 3, sub = colF & 7;
    ushort_t* innW = inng((td + 1) & 1);
#pragma unroll
    for (int v = 0; v < 4; ++v) {
      int row = rT * 16 + fq4 * 4 + v;
      float o = fa[v] + inp[v] + fcbF;
      inp[v] = o;
      if (wr) innW[(kq * 128 + row) * 8 + sub] = f2bf(o);
      if (colF < 55) outp[(size_t)(g * 128 + row) * 1375 + td * 55 + colF] = o;
    }
    asm volatile("s_waitcnt vmcnt(0)" ::: "memory");
    if (wr && l == 0) atomicAdd(fcpp(td), 1u);
  };

  arrive(1);
  wait_rel(1);  // init published (once)

  for (int t = 0; t < 74; ++t) {
#pragma unroll
    for (int i = 0; i < 12; ++i) av[i] = (f32x4){0.f, 0.f, 0.f, 0.f};
#pragma unroll
    for (int i = 0; i < 4; ++i) nx[i] = (f32x4){0.f, 0.f, 0.f, 0.f};

    if (t <= 49 && w < 4) xpart(t <= 48 ? xgg + (size_t)t * 8192 : inng(0));
    if (t >= 50 && w == 4) fcdo(hb(t & 1), t - 50, true, t + 1);
    if (t > 0) hpart(hb(t & 1), t + 1);
    if (t >= 50) {
      fc_wait(t - 50);
      if (w < 4) xpart(inng((t - 49) & 1));
    }
    kreduce();
    if (w < 4) {  // epilogue: gates + fp32 carry + publish bf16 h(t+1)
      ushort_t* hn = hb((t + 1) & 1);
#pragma unroll
      for (int mi = 0; mi < 2; ++mi)
#pragma unroll
        for (int jf = 0; jf < 2; ++jf) {
          f32x4 R_ = av[mi * 2 + jf], Z_ = av[4 + mi * 2 + jf];
          f32x4 NH = av[8 + mi * 2 + jf], NX = nx[mi * 2 + jf];
          const int kq = slot * 4 + jf * 2 + (fr >> 3), sub = fr & 7;
#pragma unroll
          for (int v = 0; v < 4; ++v) {
            float rr = sigmf(R_[v] + brz[jf]);
            float zz = sigmf(Z_[v] + bzz[jf]);
            float nn = tanhf_(NX[v] + bin[jf] + rr * (NH[v] + bhn[jf]));
            float h = (1.f - zz) * nn + zz * hreg[mi * 2 + jf][v];
            hreg[mi * 2 + jf][v] = h;
            int row = w * 32 + mi * 16 + fq4 * 4 + v;
            hn[(kq * 128 + row) * 8 + sub] = f2bf(h);
          }
        }
    }
    __syncthreads();  // drains every wave's h stores at L2
    if (tid == 0) AS(flagg + slot * 16, (unsigned)(t + 2));
  }

  if (w == 4) fcdo(hb(0), 24, false, 75);
}

extern "C" void kernel_launch(void* const* d_in, const int* in_sizes, int n_in,
                              void* d_out, int out_size, void* d_ws, size_t ws_size,
                              hipStream_t stream) {
  const float* enc  = (const float*)d_in[0];
  const float* dec  = (const float*)d_in[1];
  const float* Wih  = (const float*)d_in[2];
  const float* Whh  = (const float*)d_in[3];
  const float* b_ih = (const float*)d_in[4];
  const float* b_hh = (const float*)d_in[5];
  const float* fcw  = (const float*)d_in[6];
  const float* fcb  = (const float*)d_in[7];
  float* out = (float*)d_out;

  char* ws = (char*)d_ws;
  unsigned* cnt  = (unsigned*)ws; ws += 131072;
  ushort_t* xg   = (ushort_t*)ws; ws += (size_t)8 * 49 * 8192 * 2;   // 6.42 MB
  ushort_t* hA   = (ushort_t*)ws; ws += (size_t)8 * 2 * 131072 * 2;  // 4 MB
  ushort_t* innA = (ushort_t*)ws; ws += (size_t)8 * 2 * 8192 * 2;    // 256 KB
  ushort_t* nG   = (ushort_t*)ws; ws += (size_t)8 * 32 * 32768 * 2;  // 16 MB
  ushort_t* wiG  = (ushort_t*)ws; ws += (size_t)8 * 32 * 8192 * 2;   // 4 MB
  ushort_t* fcG  = (ushort_t*)ws; ws += (size_t)8 * 65536 * 2;       // 1 MB

  (void)hipMemsetAsync(cnt, 0, 131072, stream);
  seq2seq_xcd<<<256, 512, 0, stream>>>(
      enc, dec, Wih, Whh, b_ih, b_hh, fcw, fcb, out,
      xg, hA, innA, nG, wiG, fcG, cnt);
}